// Round 12
// baseline (141.268 us; speedup 1.0000x reference)
//
#include <hip/hip_runtime.h>
#include <math.h>

#define DD 64      // feature dim
#define MM 128     // time points per path
#define RSW 132    // inc band row stride (words): 4*RSW % 32 == 16 -> 2-way write banks
#define BUFW 2112  // one band buffer: 16*RSW words

typedef float  f32x4v __attribute__((ext_vector_type(4)));
typedef __bf16 bf16x8 __attribute__((ext_vector_type(8)));

#define FOR8(F) F(0) F(1) F(2) F(3) F(4) F(5) F(6) F(7)

union FragU { unsigned int u[4]; bf16x8 v; };

// RNE f32x2 -> packed bf16x2
__device__ __forceinline__ unsigned cvtpk(float lo, float hi) {
    unsigned r;
    asm("v_cvt_pk_bf16_f32 %0, %1, %2" : "=v"(r) : "v"(lo), "v"(hi));
    return r;
}

// bf16 frag of (row1 - row0), 8 consecutive floats (hi bits, RNE)
__device__ __forceinline__ bf16x8 dfrag_hi(const float* __restrict__ r0,
                                           const float* __restrict__ r1) {
    float4 a0 = *(const float4*)r0, a1 = *(const float4*)(r0 + 4);
    float4 b0 = *(const float4*)r1, b1 = *(const float4*)(r1 + 4);
    FragU f;
    f.u[0] = cvtpk(b0.x - a0.x, b0.y - a0.y);
    f.u[1] = cvtpk(b0.z - a0.z, b0.w - a0.w);
    f.u[2] = cvtpk(b1.x - a1.x, b1.y - a1.y);
    f.u[3] = cvtpk(b1.z - a1.z, b1.w - a1.w);
    return f.v;
}

// ---- wave64 inclusive add-scan via DPP (proven rounds 2-11) ----
template<int CTRL, int RM, bool BC>
__device__ __forceinline__ float dpp_add(float x) {
    int t = __builtin_amdgcn_update_dpp(0, __float_as_int(x), CTRL, RM, 0xf, BC);
    return x + __int_as_float(t);
}
__device__ __forceinline__ float wave_incl_scan(float x) {
    x = dpp_add<0x111, 0xf, true >(x);   // row_shr:1
    x = dpp_add<0x112, 0xf, true >(x);   // row_shr:2
    x = dpp_add<0x114, 0xf, true >(x);   // row_shr:4
    x = dpp_add<0x118, 0xf, true >(x);   // row_shr:8
    x = dpp_add<0x142, 0xa, false>(x);   // row_bcast:15 -> rows 1,3
    x = dpp_add<0x143, 0xc, false>(x);   // row_bcast:31 -> rows 2,3
    return x;
}

// ROUND 12: producer/consumer 2-wave blocks, one (gram,a,b) pair per block.
// r6-r11 evidence: every pipe <=31%, wall 4-7x busiest pipe, dur flat across
// intra-wave schedules -> latency-bound with too few resident waves (grid
// supplied 4.06/SIMD, LDS capped 2.25/SIMD) and serial phase alternation.
// Fix: wave 0 (producer) builds B-table + streams 16-row inc bands (MFMA)
// into double-buffered LDS; wave 1 (consumer) runs the DPP Goursat scan.
// Band k+1 production overlaps band k scan (per-band time = max, not sum);
// grid 8256 blocks x 2 waves = 16/SIMD supply, 9 blocks/CU (16.9 KB LDS)
// = 4.5 waves/SIMD resident.
// Barriers: producer calls 8 (after each band), consumer 8 (before each
// scan); buf[k&1] overwrite at band k+2 is sealed by barrier k+1.
__global__ __launch_bounds__(128, 4) void sig_goursat_kernel(
        const float* __restrict__ X, const float* __restrict__ Y,
        float* __restrict__ Kout)
{
    const int bid = blockIdx.x;
    int g, a, b;
    if (bid < 4160) {                  // symmetric grams, triangular index
        g = bid < 2080 ? 0 : 1;
        const int t = bid - g * 2080;
        float sq = sqrtf(4160.25f - 2.0f * (float)t);
        a = (int)(64.5f - sq);
        if (a < 0) a = 0; if (a > 63) a = 63;
        while (a > 0  && (a * (129 - a)) / 2 > t) --a;
        while (a < 63 && ((a + 1) * (128 - a)) / 2 <= t) ++a;
        b = a + (t - (a * (129 - a)) / 2);
    } else {
        const int t = bid - 4160;
        g = 2; a = t >> 6; b = t & 63;
    }

    const int tid  = threadIdx.x;
    const int wid  = tid >> 6;
    const int lane = tid & 63;

    __shared__ float buf[2][BUFW];     // double-buffered 16-row inc bands

    if (wid == 0) {
        // ================= PRODUCER =================
        const float* __restrict__ U = (g == 1 ? Y : X) + (size_t)a * (MM * DD);
        const float* __restrict__ V = (g == 0 ? X : Y) + (size_t)b * (MM * DD);
        const int l15  = lane & 15;
        const int k8   = (lane >> 4) * 8;
        const int rowg = (lane >> 4) * 4;
        const int wbase = rowg * RSW + l15;    // 4*RSW%32==16 -> 2-way banks

        // B-frag register table: 16 named bf16x8 (64 regs), built once
#define TBDECL(ct) bf16x8 tb0_##ct, tb1_##ct;
        FOR8(TBDECL)
#define TBUILD(ct) { int brow_ = ct * 16 + l15; if (brow_ > 126) brow_ = 126; \
        const float* vp_ = V + (size_t)brow_ * DD + k8; \
        tb0_##ct = dfrag_hi(vp_,      vp_ + DD); \
        tb1_##ct = dfrag_hi(vp_ + 32, vp_ + DD + 32); }
        FOR8(TBUILD)

#define CTSTEP(ct) { f32x4v c = {0.f, 0.f, 0.f, 0.f}; \
        c = __builtin_amdgcn_mfma_f32_16x16x32_bf16(ak0, tb0_##ct, c, 0, 0, 0); \
        c = __builtin_amdgcn_mfma_f32_16x16x32_bf16(ak1, tb1_##ct, c, 0, 0, 0); \
        const int w_ = wbase + ct * 16; \
        bp[w_]         = c[0]; \
        bp[w_ + RSW]   = c[1]; \
        bp[w_ + 2*RSW] = c[2]; \
        bp[w_ + 3*RSW] = c[3]; }

        for (int band = 0; band < 8; ++band) {
            int arow = band * 16 + l15; if (arow > 126) arow = 126;
            const float* ap = U + (size_t)arow * DD + k8;
            bf16x8 ak0 = dfrag_hi(ap,      ap + DD);
            bf16x8 ak1 = dfrag_hi(ap + 32, ap + DD + 32);
            float* bp = buf[band & 1];
            FOR8(CTSTEP)
            __syncthreads();
        }
    } else {
        // ================= CONSUMER =================
        float KL0 = 1.0f, KL1 = 1.0f;          // K[0][2l], K[0][2l+1] = 1

#define SCANROW1(e) { \
        const float m0 = e.x * KL0; \
        const float m1 = e.y * KL1; \
        const float t_ = m0 + m1; \
        const float S_ = wave_incl_scan(t_); \
        const float ex = S_ - t_; \
        KL1 += ex + m0; \
        KL0 += ex; }

        for (int band = 0; band < 7; ++band) {
            __syncthreads();                   // band ready
            const float2* pl = (const float2*)&buf[band & 1][2 * lane];
            float2 e = pl[0];                  // row 0 (stride 66 float2s)
            float2 f = pl[66];                 // row 1
            #pragma unroll
            for (int r = 0; r < 14; ++r) {     // depth-2 LDS prefetch
                float2 n = pl[(r + 2) * 66];
                SCANROW1(e)
                e = f; f = n;
            }
            SCANROW1(e)                        // row 14
            SCANROW1(f)                        // row 15
        }
        {
            __syncthreads();                   // band 7 ready (15 real rows)
            const float2* pl = (const float2*)&buf[1][2 * lane];
            float2 e = pl[0];
            float2 f = pl[66];
            #pragma unroll
            for (int r = 0; r < 13; ++r) {
                float2 n = pl[(r + 2) * 66];
                SCANROW1(e)
                e = f; f = n;
            }
            SCANROW1(e)                        // row 13
            SCANROW1(f)                        // row 14  (p=127 is phantom)
        }

        if (lane == 63) Kout[(size_t)g * 4096 + a * 64 + b] = KL1; // K[127][127]
    }
}

// Deterministic weighted reduction + the mean((X0-Y0)^2) term.
__global__ void sig_reduce_kernel(const float* __restrict__ X,
                                  const float* __restrict__ Y,
                                  const float* __restrict__ Kws,
                                  float* __restrict__ out)
{
    const int t = threadIdx.x;
    double accK = 0.0, acc2 = 0.0;
    for (int i = t; i < 4096; i += 256) {
        const int a = i >> 6, b = i & 63;
        if (a <= b) {
            const double w = (a == b) ? 1.0 : 2.0;
            accK += w * (double)Kws[i];           // XX
            accK += w * (double)Kws[4096 + i];    // YY
        }
        accK -= 2.0 * (double)Kws[8192 + i];      // XY
        const float df = X[(size_t)a * (MM * DD) + b] - Y[(size_t)a * (MM * DD) + b];
        acc2 += (double)df * (double)df;
    }
    __shared__ double red[256];
    red[t] = accK / 4096.0 + acc2 / 4096.0;
    __syncthreads();
    for (int s = 128; s > 0; s >>= 1) {
        if (t < s) red[t] += red[t + s];
        __syncthreads();
    }
    if (t == 0) out[0] = (float)red[0];
}

extern "C" void kernel_launch(void* const* d_in, const int* in_sizes, int n_in,
                              void* d_out, int out_size, void* d_ws, size_t ws_size,
                              hipStream_t stream) {
    const float* X = (const float*)d_in[0];
    const float* Y = (const float*)d_in[1];
    float* Kws = (float*)d_ws;          // 3 * 4096 floats
    float* out = (float*)d_out;

    sig_goursat_kernel<<<dim3(8256), dim3(128), 0, stream>>>(X, Y, Kws);
    sig_reduce_kernel<<<dim3(1), dim3(256), 0, stream>>>(X, Y, Kws, out);
}